// Round 7
// baseline (999.666 us; speedup 1.0000x reference)
//
#include <hip/hip_runtime.h>
#include <hip/hip_bf16.h>
#include <cstdint>

typedef unsigned long long ull;

// packed[d]: high 32 = count, low 32 = fixed-point (x 2^22) weighted degree sum.
#define FIXS 4194304.0f

__device__ __forceinline__ void fma4(float4& a, float s, const float4& v) {
    a.x += s * v.x; a.y += s * v.y; a.z += s * v.z; a.w += s * v.w;
}

__device__ __forceinline__ float dinv_of(ull q) {
    return rsqrtf((float)(unsigned)(q & 0xffffffffULL) * (1.0f / FIXS) + 1.0f);
}

// ---------------- device bodies ----------------

__device__ __forceinline__ void edge_body(int e, const int* __restrict__ ei, const float* __restrict__ w,
                                          ull* __restrict__ packed, int2* __restrict__ ell, int CAP, int E) {
    if (e >= E) return;
    int s = ei[e], d = ei[E + e];
    float wv = w[e];
    ull inc = (1ULL << 32) | (ull)(unsigned)(wv * FIXS + 0.5f);
    ull old = atomicAdd(&packed[d], inc);
    int pos = (int)(old >> 32);
    if (pos < CAP) ell[(size_t)d * CAP + pos] = make_int2(s, __float_as_int(wv));
}

// GEMM H[N,96] = X[N,96] @ W[96,96], 256 threads, 128 rows/block.
__device__ __forceinline__ void gemm_body(float* Ws, int bb, const float* __restrict__ X,
                                          const float* __restrict__ W, float* __restrict__ H, int N) {
    int t = threadIdx.x;
    {
        const float4* Wg = (const float4*)W;
        float4* Wl = (float4*)Ws;
        for (int i = t; i < 2304; i += 256) Wl[i] = Wg[i];
    }
    int lane = t & 63, wv = t >> 6;
    int cb = wv * 6;
    int row0 = bb * 128;
    int rA = row0 + lane, rB = row0 + 64 + lane;
    bool vA = rA < N, vB = rB < N;
    const float* xA = X + (size_t)(vA ? rA : 0) * 96;
    const float* xB = X + (size_t)(vB ? rB : 0) * 96;
    __syncthreads();
    float4 aA[6] = {}, aB[6] = {};
    const float4* W4 = (const float4*)Ws;
    for (int k0 = 0; k0 < 96; k0 += 4) {
        float4 xa = *(const float4*)(xA + k0);
        float4 xb = *(const float4*)(xB + k0);
#pragma unroll
        for (int kk = 0; kk < 4; kk++) {
            float sa = (kk == 0) ? xa.x : (kk == 1) ? xa.y : (kk == 2) ? xa.z : xa.w;
            float sb = (kk == 0) ? xb.x : (kk == 1) ? xb.y : (kk == 2) ? xb.z : xb.w;
#pragma unroll
            for (int c = 0; c < 6; c++) {
                float4 wv4 = W4[(k0 + kk) * 24 + cb + c];
                fma4(aA[c], sa, wv4);
                fma4(aB[c], sb, wv4);
            }
        }
    }
    if (vA) {
        float4* o = (float4*)(H + (size_t)rA * 96 + wv * 24);
#pragma unroll
        for (int c = 0; c < 6; c++) o[c] = aA[c];
    }
    if (vB) {
        float4* o = (float4*)(H + (size_t)rB * 96 + wv * 24);
#pragma unroll
        for (int c = 0; c < 6; c++) o[c] = aB[c];
    }
}

// leaders write counts and (N-n) max so first[g] = N - firstmax[g]; zero-init friendly.
__device__ __forceinline__ void pool_meta_body(int bb, const int* __restrict__ batch,
                                               int* __restrict__ cnts, int* __restrict__ firstmax, int N) {
    int n = bb * 256 + threadIdx.x;
    int lane = threadIdx.x & 63;
    bool valid = n < N;
    int g = valid ? batch[n] : -1;
    int gp = __shfl_up(g, 1);
    bool leader = valid && (lane == 0 || gp != g);
    ull lm = __ballot(leader);
    if (leader) {
        ull higher = (lane == 63) ? 0ULL : (lm >> (lane + 1));
        int run;
        if (higher) {
            run = __ffsll((long long)higher);
        } else {
            int waveBase = n - lane;
            int validLanes = min(64, N - waveBase);
            run = validLanes - lane;
        }
        atomicAdd(&cnts[g], run);
        atomicMax(&firstmax[g], N - n);
    }
}

// ---------------- phase 1: GEMM1 || pool_meta || edge scatter ----------------
__global__ __launch_bounds__(256) void k_phase1(const float* __restrict__ X, const float* __restrict__ W1,
                                                float* __restrict__ H,
                                                const int* __restrict__ ei, const float* __restrict__ w,
                                                ull* __restrict__ packed, int2* __restrict__ ell, int CAP, int E,
                                                const int* __restrict__ batch, int* __restrict__ cnts,
                                                int* __restrict__ firstmax, int N, int GB, int PB) {
    __shared__ __align__(16) float Ws[96 * 96];
    int b = blockIdx.x;
    if (b < GB) {
        gemm_body(Ws, b, X, W1, H, N);
    } else if (b < GB + PB) {
        pool_meta_body(b - GB, batch, cnts, firstmax, N);
    } else {
        edge_body((b - GB - PB) * 256 + threadIdx.x, ei, w, packed, ell, CAP, E);
    }
}

// ---------------- k_mid: layer-1 aggregation + bias + relu + GEMM2, fused ----------------
// 8 nodes x 32 lanes. After gather, the 32-lane group holds the relu'd row in registers
// (lanes 0-23: float4 each). Broadcast row elems via shfl(width=32) against LDS W2.
__global__ __launch_bounds__(256) void k_mid(const float* __restrict__ h, const int2* __restrict__ ell,
                                             const ull* __restrict__ packed, int CAP,
                                             const float* __restrict__ bias, const float* __restrict__ W2,
                                             float* __restrict__ h2, int N) {
    __shared__ __align__(16) float Wl[96 * 100];   // row stride 100 floats: breaks bank pattern
    int t = threadIdx.x;
    {
        const float4* Wg = (const float4*)W2;
        for (int i = t; i < 2304; i += 256) {
            int r = i / 24, c = i % 24;
            *(float4*)&Wl[r * 100 + c * 4] = Wg[i];
        }
    }
    __syncthreads();
    int slot = t >> 5, j = t & 31;
    int jj = (j < 24) ? j : 23;
    int n = blockIdx.x * 8 + slot;
    float4 acc = {0, 0, 0, 0};
    if (n < N) {
        ull pn = packed[n];
        int c = (int)(pn >> 32);
        float dn = dinv_of(pn), d2 = dn * dn;
        const float4* h4 = (const float4*)h;
        acc = h4[(size_t)n * 24 + jj];
        acc.x *= d2; acc.y *= d2; acc.z *= d2; acc.w *= d2;
        size_t base = (size_t)n * CAP;
        int i = 0;
        for (; i + 4 <= c; i += 4) {
            int4 p0 = *(const int4*)(ell + base + i);
            int4 p1 = *(const int4*)(ell + base + i + 2);
            ull q0 = packed[p0.x], q1 = packed[p0.z], q2 = packed[p1.x], q3 = packed[p1.z];
            float4 v0 = h4[(size_t)p0.x * 24 + jj];
            float4 v1 = h4[(size_t)p0.z * 24 + jj];
            float4 v2 = h4[(size_t)p1.x * 24 + jj];
            float4 v3 = h4[(size_t)p1.z * 24 + jj];
            fma4(acc, dinv_of(q0) * __int_as_float(p0.y) * dn, v0);
            fma4(acc, dinv_of(q1) * __int_as_float(p0.w) * dn, v1);
            fma4(acc, dinv_of(q2) * __int_as_float(p1.y) * dn, v2);
            fma4(acc, dinv_of(q3) * __int_as_float(p1.w) * dn, v3);
        }
        for (; i < c; i++) {
            int2 ev = ell[base + i];
            ull q = packed[ev.x];
            fma4(acc, dinv_of(q) * __int_as_float(ev.y) * dn, h4[(size_t)ev.x * 24 + jj]);
        }
        float4 b4 = ((const float4*)bias)[jj];
        acc.x = fmaxf(acc.x + b4.x, 0.f); acc.y = fmaxf(acc.y + b4.y, 0.f);
        acc.z = fmaxf(acc.z + b4.z, 0.f); acc.w = fmaxf(acc.w + b4.w, 0.f);
    }
    // GEMM2: out = acc_row @ W2 (row broadcast via shfl within the 32-lane group)
    float4 out = {0, 0, 0, 0};
#pragma unroll 4
    for (int k0 = 0; k0 < 96; k0 += 4) {
        int src = k0 >> 2;
        float4 s4 = make_float4(__shfl(acc.x, src, 32), __shfl(acc.y, src, 32),
                                __shfl(acc.z, src, 32), __shfl(acc.w, src, 32));
#pragma unroll
        for (int kk = 0; kk < 4; kk++) {
            float s = (kk == 0) ? s4.x : (kk == 1) ? s4.y : (kk == 2) ? s4.z : s4.w;
            float4 wv4 = *(const float4*)&Wl[(k0 + kk) * 100 + jj * 4];
            fma4(out, s, wv4);
        }
    }
    if (n < N && j < 24) ((float4*)h2)[(size_t)n * 24 + j] = out;
}

// ---------------- Layer-2 aggregation + mean-pool; last block runs the head ----------------
__global__ __launch_bounds__(256) void k_agg_pool(const float* __restrict__ h, const int2* __restrict__ ell,
                                                  const ull* __restrict__ packed, int CAP,
                                                  const float* __restrict__ bias,
                                                  const int* __restrict__ batch, float* __restrict__ sums,
                                                  int* __restrict__ done, int nblocks, int N,
                                                  const int* __restrict__ cnts, const int* __restrict__ firstmax,
                                                  const float* __restrict__ metadata,
                                                  const float* __restrict__ Wm, const float* __restrict__ bm,
                                                  const float* __restrict__ Wf, const float* __restrict__ bf,
                                                  float* __restrict__ out, int G, int mrows) {
    __shared__ float vals[8][96];
    __shared__ int gs[8];
    __shared__ float z[192];
    __shared__ int amLast;
    int slot = threadIdx.x >> 5, j = threadIdx.x & 31;
    int jj = (j < 24) ? j : 23;
    int n = blockIdx.x * 8 + slot;
    float4 acc = {0, 0, 0, 0};
    int g = -1;
    if (n < N) {
        g = batch[n];
        ull pn = packed[n];
        int c = (int)(pn >> 32);
        float dn = dinv_of(pn), d2 = dn * dn;
        const float4* h4 = (const float4*)h;
        acc = h4[(size_t)n * 24 + jj];
        acc.x *= d2; acc.y *= d2; acc.z *= d2; acc.w *= d2;
        size_t base = (size_t)n * CAP;
        int i = 0;
        for (; i + 4 <= c; i += 4) {
            int4 p0 = *(const int4*)(ell + base + i);
            int4 p1 = *(const int4*)(ell + base + i + 2);
            ull q0 = packed[p0.x], q1 = packed[p0.z], q2 = packed[p1.x], q3 = packed[p1.z];
            float4 v0 = h4[(size_t)p0.x * 24 + jj];
            float4 v1 = h4[(size_t)p0.z * 24 + jj];
            float4 v2 = h4[(size_t)p1.x * 24 + jj];
            float4 v3 = h4[(size_t)p1.z * 24 + jj];
            fma4(acc, dinv_of(q0) * __int_as_float(p0.y) * dn, v0);
            fma4(acc, dinv_of(q1) * __int_as_float(p0.w) * dn, v1);
            fma4(acc, dinv_of(q2) * __int_as_float(p1.y) * dn, v2);
            fma4(acc, dinv_of(q3) * __int_as_float(p1.w) * dn, v3);
        }
        for (; i < c; i++) {
            int2 ev = ell[base + i];
            ull q = packed[ev.x];
            fma4(acc, dinv_of(q) * __int_as_float(ev.y) * dn, h4[(size_t)ev.x * 24 + jj]);
        }
        float4 b4 = ((const float4*)bias)[jj];
        acc.x = fmaxf(acc.x + b4.x, 0.f); acc.y = fmaxf(acc.y + b4.y, 0.f);
        acc.z = fmaxf(acc.z + b4.z, 0.f); acc.w = fmaxf(acc.w + b4.w, 0.f);
    }
    if (j == 0) gs[slot] = g;
    if (j < 24) *(float4*)&vals[slot][4 * j] = acc;
    __syncthreads();
    if (threadIdx.x < 96) {
        int f = threadIdx.x;
        int g0 = gs[0];
        bool uni = true;
#pragma unroll
        for (int s = 1; s < 8; s++) uni &= (gs[s] == g0);
        if (uni) {
            if (g0 >= 0) {
                float sum = 0;
#pragma unroll
                for (int s = 0; s < 8; s++) sum += vals[s][f];
                atomicAdd(&sums[g0 * 96 + f], sum);
            }
        } else {
#pragma unroll
            for (int s = 0; s < 8; s++) {
                int gg = gs[s];
                if (gg >= 0) atomicAdd(&sums[gg * 96 + f], vals[s][f]);
            }
        }
    }
    // ---- last block runs the head (pooled mean + metadata MLP + final linear) ----
    __syncthreads();
    __threadfence();
    if (threadIdx.x == 0) amLast = (atomicAdd(done, 1) == nblocks - 1) ? 1 : 0;
    __syncthreads();
    if (!amLast) return;
    __threadfence();
    int t = threadIdx.x;
    for (int gg = 0; gg < G; gg++) {
        if (t < 96) {
            float sv = __hip_atomic_load(&sums[gg * 96 + t], __ATOMIC_RELAXED, __HIP_MEMORY_SCOPE_AGENT);
            float c = fmaxf((float)cnts[gg], 1.0f);
            z[t] = sv / c;
            unsigned fi = (unsigned)(N - firstmax[gg]);
            unsigned mi = fi % (unsigned)mrows;   // mrows = metadata.shape[0] = G
            float a = bm[t];
            for (int k = 0; k < 30; k++) a += metadata[mi * 30 + k] * Wm[k * 96 + t];
            z[96 + t] = fmaxf(a, 0.f);
        }
        __syncthreads();
        if (t < 10) {
            float a = bf[t];
            for (int q = 0; q < 192; q++) a += z[q] * Wf[q * 10 + t];
            out[gg * 10 + t] = a;
        }
        __syncthreads();
    }
}

extern "C" void kernel_launch(void* const* d_in, const int* in_sizes, int n_in,
                              void* d_out, int out_size, void* d_ws, size_t ws_size,
                              hipStream_t stream) {
    const float* x        = (const float*)d_in[0];
    const int*   ei       = (const int*)d_in[1];
    const float* ew       = (const float*)d_in[2];
    const int*   batch    = (const int*)d_in[3];
    const float* metadata = (const float*)d_in[4];
    const float* W1 = (const float*)d_in[5];
    const float* b1 = (const float*)d_in[6];
    const float* W2 = (const float*)d_in[7];
    const float* b2 = (const float*)d_in[8];
    const float* Wm = (const float*)d_in[9];
    const float* bm = (const float*)d_in[10];
    const float* Wf = (const float*)d_in[11];
    const float* bf = (const float*)d_in[12];
    float* out = (float*)d_out;

    const int N = in_sizes[3];
    const int E = in_sizes[2];
    const int G = in_sizes[4] / 30;   // metadata rows (metadata.shape[0])

    auto al = [](size_t b) { return (b + 255) & ~(size_t)255; };
    size_t fixed = al((size_t)N * 8) + al((size_t)G * 96 * 4) + al((size_t)G * 4) * 2 + al(256) +
                   al((size_t)N * 96 * 4) * 2 + 4096;
    int CAP = 64;
    while (CAP > 32 && fixed + al((size_t)N * CAP * 8) > ws_size) CAP -= 8;
    if (CAP > 48) CAP = 48;

    char* p = (char*)d_ws;
    size_t off = 0;
    auto carve = [&](size_t bytes) -> void* {
        void* r = p + off;
        off = (off + bytes + 255) & ~(size_t)255;
        return r;
    };
    // zero-init region: packed | sums | cnts | firstmax | done  (single memset)
    ull*   packed   = (ull*)carve((size_t)N * 8);
    float* sums     = (float*)carve((size_t)G * 96 * 4);
    int*   cnts     = (int*)carve((size_t)G * 4);
    int*   firstmax = (int*)carve((size_t)G * 4);
    int*   done     = (int*)carve(256);
    size_t zero_end = off;
    int2*  ell  = (int2*)carve((size_t)N * CAP * 8);
    float* hbuf = (float*)carve((size_t)N * 96 * 4);
    float* h2   = (float*)carve((size_t)N * 96 * 4);

    hipMemsetAsync(packed, 0, zero_end, stream);

    int EB = (E + 255) / 256;
    int GB = (N + 127) / 128;
    int PB = (N + 255) / 256;
    int nb8 = (N + 7) / 8;

    // phase 1: GEMM1 (x@W1) || per-graph counts/first || edge scatter — all independent
    k_phase1<<<GB + PB + EB, 256, 0, stream>>>(x, W1, hbuf, ei, ew, packed, ell, CAP, E,
                                               batch, cnts, firstmax, N, GB, PB);
    // layer-1 aggregation + relu + GEMM2 fused
    k_mid<<<nb8, 256, 0, stream>>>(hbuf, ell, packed, CAP, b1, W2, h2, N);
    // layer-2 aggregation + mean-pool; last block computes the head
    k_agg_pool<<<nb8, 256, 0, stream>>>(h2, ell, packed, CAP, b2, batch, sums,
                                        done, nb8, N, cnts, firstmax, metadata,
                                        Wm, bm, Wf, bf, out, G, G);   // mrows = G (was 30: the R6 bug)
}

// Round 8
// 279.304 us; speedup vs baseline: 3.5791x; 3.5791x over previous
//
#include <hip/hip_runtime.h>
#include <hip/hip_bf16.h>
#include <cstdint>

typedef unsigned long long ull;

// packed[d]: high 32 = count, low 32 = fixed-point (x 2^22) weighted degree sum.
#define FIXS 4194304.0f

__device__ __forceinline__ void fma4(float4& a, float s, const float4& v) {
    a.x += s * v.x; a.y += s * v.y; a.z += s * v.z; a.w += s * v.w;
}

__device__ __forceinline__ float dinv_of(ull q) {
    return rsqrtf((float)(unsigned)(q & 0xffffffffULL) * (1.0f / FIXS) + 1.0f);
}

// ---------------- device bodies ----------------

__device__ __forceinline__ void edge_body(int e, const int* __restrict__ ei, const float* __restrict__ w,
                                          ull* __restrict__ packed, int2* __restrict__ ell, int CAP, int E) {
    if (e >= E) return;
    int s = ei[e], d = ei[E + e];
    float wv = w[e];
    ull inc = (1ULL << 32) | (ull)(unsigned)(wv * FIXS + 0.5f);
    ull old = atomicAdd(&packed[d], inc);
    int pos = (int)(old >> 32);
    if (pos < CAP) ell[(size_t)d * CAP + pos] = make_int2(s, __float_as_int(wv));
}

// GEMM H[N,96] = X[N,96] @ W[96,96], 256 threads, 128 rows/block.
__device__ __forceinline__ void gemm_body(float* Ws, int bb, const float* __restrict__ X,
                                          const float* __restrict__ W, float* __restrict__ H, int N) {
    int t = threadIdx.x;
    {
        const float4* Wg = (const float4*)W;
        float4* Wl = (float4*)Ws;
        for (int i = t; i < 2304; i += 256) Wl[i] = Wg[i];
    }
    int lane = t & 63, wv = t >> 6;
    int cb = wv * 6;
    int row0 = bb * 128;
    int rA = row0 + lane, rB = row0 + 64 + lane;
    bool vA = rA < N, vB = rB < N;
    const float* xA = X + (size_t)(vA ? rA : 0) * 96;
    const float* xB = X + (size_t)(vB ? rB : 0) * 96;
    __syncthreads();
    float4 aA[6] = {}, aB[6] = {};
    const float4* W4 = (const float4*)Ws;
    for (int k0 = 0; k0 < 96; k0 += 4) {
        float4 xa = *(const float4*)(xA + k0);
        float4 xb = *(const float4*)(xB + k0);
#pragma unroll
        for (int kk = 0; kk < 4; kk++) {
            float sa = (kk == 0) ? xa.x : (kk == 1) ? xa.y : (kk == 2) ? xa.z : xa.w;
            float sb = (kk == 0) ? xb.x : (kk == 1) ? xb.y : (kk == 2) ? xb.z : xb.w;
#pragma unroll
            for (int c = 0; c < 6; c++) {
                float4 wv4 = W4[(k0 + kk) * 24 + cb + c];
                fma4(aA[c], sa, wv4);
                fma4(aB[c], sb, wv4);
            }
        }
    }
    if (vA) {
        float4* o = (float4*)(H + (size_t)rA * 96 + wv * 24);
#pragma unroll
        for (int c = 0; c < 6; c++) o[c] = aA[c];
    }
    if (vB) {
        float4* o = (float4*)(H + (size_t)rB * 96 + wv * 24);
#pragma unroll
        for (int c = 0; c < 6; c++) o[c] = aB[c];
    }
}

// leaders write counts and (N-n) max so first[g] = N - firstmax[g]; zero-init friendly.
__device__ __forceinline__ void pool_meta_body(int bb, const int* __restrict__ batch,
                                               int* __restrict__ cnts, int* __restrict__ firstmax, int N) {
    int n = bb * 256 + threadIdx.x;
    int lane = threadIdx.x & 63;
    bool valid = n < N;
    int g = valid ? batch[n] : -1;
    int gp = __shfl_up(g, 1);
    bool leader = valid && (lane == 0 || gp != g);
    ull lm = __ballot(leader);
    if (leader) {
        ull higher = (lane == 63) ? 0ULL : (lm >> (lane + 1));
        int run;
        if (higher) {
            run = __ffsll((long long)higher);
        } else {
            int waveBase = n - lane;
            int validLanes = min(64, N - waveBase);
            run = validLanes - lane;
        }
        atomicAdd(&cnts[g], run);
        atomicMax(&firstmax[g], N - n);
    }
}

// ---------------- phase 1: GEMM1 || pool_meta || edge scatter ----------------
__global__ __launch_bounds__(256) void k_phase1(const float* __restrict__ X, const float* __restrict__ W1,
                                                float* __restrict__ H,
                                                const int* __restrict__ ei, const float* __restrict__ w,
                                                ull* __restrict__ packed, int2* __restrict__ ell, int CAP, int E,
                                                const int* __restrict__ batch, int* __restrict__ cnts,
                                                int* __restrict__ firstmax, int N, int GB, int PB) {
    __shared__ __align__(16) float Ws[96 * 96];
    int b = blockIdx.x;
    if (b < GB) {
        gemm_body(Ws, b, X, W1, H, N);
    } else if (b < GB + PB) {
        pool_meta_body(b - GB, batch, cnts, firstmax, N);
    } else {
        edge_body((b - GB - PB) * 256 + threadIdx.x, ei, w, packed, ell, CAP, E);
    }
}

// ---------------- k_mid: layer-1 aggregation + bias + relu + GEMM2, fused ----------------
// 8 nodes x 32 lanes. After gather, the 32-lane group holds the relu'd row in registers
// (lanes 0-23: float4 each). Broadcast row elems via shfl(width=32) against LDS W2.
__global__ __launch_bounds__(256) void k_mid(const float* __restrict__ h, const int2* __restrict__ ell,
                                             const ull* __restrict__ packed, int CAP,
                                             const float* __restrict__ bias, const float* __restrict__ W2,
                                             float* __restrict__ h2, int N) {
    __shared__ __align__(16) float Wl[96 * 100];   // row stride 100 floats: breaks bank pattern
    int t = threadIdx.x;
    {
        const float4* Wg = (const float4*)W2;
        for (int i = t; i < 2304; i += 256) {
            int r = i / 24, c = i % 24;
            *(float4*)&Wl[r * 100 + c * 4] = Wg[i];
        }
    }
    __syncthreads();
    int slot = t >> 5, j = t & 31;
    int jj = (j < 24) ? j : 23;
    int n = blockIdx.x * 8 + slot;
    float4 acc = {0, 0, 0, 0};
    if (n < N) {
        ull pn = packed[n];
        int c = (int)(pn >> 32);
        float dn = dinv_of(pn), d2 = dn * dn;
        const float4* h4 = (const float4*)h;
        acc = h4[(size_t)n * 24 + jj];
        acc.x *= d2; acc.y *= d2; acc.z *= d2; acc.w *= d2;
        size_t base = (size_t)n * CAP;
        int i = 0;
        for (; i + 4 <= c; i += 4) {
            int4 p0 = *(const int4*)(ell + base + i);
            int4 p1 = *(const int4*)(ell + base + i + 2);
            ull q0 = packed[p0.x], q1 = packed[p0.z], q2 = packed[p1.x], q3 = packed[p1.z];
            float4 v0 = h4[(size_t)p0.x * 24 + jj];
            float4 v1 = h4[(size_t)p0.z * 24 + jj];
            float4 v2 = h4[(size_t)p1.x * 24 + jj];
            float4 v3 = h4[(size_t)p1.z * 24 + jj];
            fma4(acc, dinv_of(q0) * __int_as_float(p0.y) * dn, v0);
            fma4(acc, dinv_of(q1) * __int_as_float(p0.w) * dn, v1);
            fma4(acc, dinv_of(q2) * __int_as_float(p1.y) * dn, v2);
            fma4(acc, dinv_of(q3) * __int_as_float(p1.w) * dn, v3);
        }
        for (; i < c; i++) {
            int2 ev = ell[base + i];
            ull q = packed[ev.x];
            fma4(acc, dinv_of(q) * __int_as_float(ev.y) * dn, h4[(size_t)ev.x * 24 + jj]);
        }
        float4 b4 = ((const float4*)bias)[jj];
        acc.x = fmaxf(acc.x + b4.x, 0.f); acc.y = fmaxf(acc.y + b4.y, 0.f);
        acc.z = fmaxf(acc.z + b4.z, 0.f); acc.w = fmaxf(acc.w + b4.w, 0.f);
    }
    // GEMM2: out = acc_row @ W2 (row broadcast via shfl within the 32-lane group)
    float4 out = {0, 0, 0, 0};
#pragma unroll 4
    for (int k0 = 0; k0 < 96; k0 += 4) {
        int src = k0 >> 2;
        float4 s4 = make_float4(__shfl(acc.x, src, 32), __shfl(acc.y, src, 32),
                                __shfl(acc.z, src, 32), __shfl(acc.w, src, 32));
#pragma unroll
        for (int kk = 0; kk < 4; kk++) {
            float s = (kk == 0) ? s4.x : (kk == 1) ? s4.y : (kk == 2) ? s4.z : s4.w;
            float4 wv4 = *(const float4*)&Wl[(k0 + kk) * 100 + jj * 4];
            fma4(out, s, wv4);
        }
    }
    if (n < N && j < 24) ((float4*)h2)[(size_t)n * 24 + j] = out;
}

// ---------------- Layer-2 aggregation + mean-pool partial sums ----------------
__global__ __launch_bounds__(256) void k_agg_pool(const float* __restrict__ h, const int2* __restrict__ ell,
                                                  const ull* __restrict__ packed, int CAP,
                                                  const float* __restrict__ bias,
                                                  const int* __restrict__ batch, float* __restrict__ sums, int N) {
    __shared__ float vals[8][96];
    __shared__ int gs[8];
    int slot = threadIdx.x >> 5, j = threadIdx.x & 31;
    int jj = (j < 24) ? j : 23;
    int n = blockIdx.x * 8 + slot;
    float4 acc = {0, 0, 0, 0};
    int g = -1;
    if (n < N) {
        g = batch[n];
        ull pn = packed[n];
        int c = (int)(pn >> 32);
        float dn = dinv_of(pn), d2 = dn * dn;
        const float4* h4 = (const float4*)h;
        acc = h4[(size_t)n * 24 + jj];
        acc.x *= d2; acc.y *= d2; acc.z *= d2; acc.w *= d2;
        size_t base = (size_t)n * CAP;
        int i = 0;
        for (; i + 4 <= c; i += 4) {
            int4 p0 = *(const int4*)(ell + base + i);
            int4 p1 = *(const int4*)(ell + base + i + 2);
            ull q0 = packed[p0.x], q1 = packed[p0.z], q2 = packed[p1.x], q3 = packed[p1.z];
            float4 v0 = h4[(size_t)p0.x * 24 + jj];
            float4 v1 = h4[(size_t)p0.z * 24 + jj];
            float4 v2 = h4[(size_t)p1.x * 24 + jj];
            float4 v3 = h4[(size_t)p1.z * 24 + jj];
            fma4(acc, dinv_of(q0) * __int_as_float(p0.y) * dn, v0);
            fma4(acc, dinv_of(q1) * __int_as_float(p0.w) * dn, v1);
            fma4(acc, dinv_of(q2) * __int_as_float(p1.y) * dn, v2);
            fma4(acc, dinv_of(q3) * __int_as_float(p1.w) * dn, v3);
        }
        for (; i < c; i++) {
            int2 ev = ell[base + i];
            ull q = packed[ev.x];
            fma4(acc, dinv_of(q) * __int_as_float(ev.y) * dn, h4[(size_t)ev.x * 24 + jj]);
        }
        float4 b4 = ((const float4*)bias)[jj];
        acc.x = fmaxf(acc.x + b4.x, 0.f); acc.y = fmaxf(acc.y + b4.y, 0.f);
        acc.z = fmaxf(acc.z + b4.z, 0.f); acc.w = fmaxf(acc.w + b4.w, 0.f);
    }
    if (j == 0) gs[slot] = g;
    if (j < 24) *(float4*)&vals[slot][4 * j] = acc;
    __syncthreads();
    if (threadIdx.x < 96) {
        int f = threadIdx.x;
        int g0 = gs[0];
        bool uni = true;
#pragma unroll
        for (int s = 1; s < 8; s++) uni &= (gs[s] == g0);
        if (uni) {
            if (g0 >= 0) {
                float sum = 0;
#pragma unroll
                for (int s = 0; s < 8; s++) sum += vals[s][f];
                atomicAdd(&sums[g0 * 96 + f], sum);
            }
        } else {
#pragma unroll
            for (int s = 0; s < 8; s++) {
                int gg = gs[s];
                if (gg >= 0) atomicAdd(&sums[gg * 96 + f], vals[s][f]);
            }
        }
    }
}

// ---------------- final: pooled mean + metadata MLP + head ----------------
__global__ __launch_bounds__(128) void k_final(const float* __restrict__ sums, const int* __restrict__ cnts,
                                               const int* __restrict__ firstmax, const float* __restrict__ metadata,
                                               const float* __restrict__ Wm, const float* __restrict__ bm,
                                               const float* __restrict__ Wf, const float* __restrict__ bf,
                                               float* __restrict__ out, int N, int mrows) {
    __shared__ float z[192];
    int g = blockIdx.x, t = threadIdx.x;
    if (t < 96) {
        float c = fmaxf((float)cnts[g], 1.0f);
        z[t] = sums[g * 96 + t] / c;
        unsigned fi = (unsigned)(N - firstmax[g]);
        unsigned mi = fi % (unsigned)mrows;   // mrows = metadata.shape[0] = G
        float acc = bm[t];
        for (int k = 0; k < 30; k++) acc += metadata[mi * 30 + k] * Wm[k * 96 + t];
        z[96 + t] = fmaxf(acc, 0.f);
    }
    __syncthreads();
    if (t < 10) {
        float acc = bf[t];
        for (int q = 0; q < 192; q++) acc += z[q] * Wf[q * 10 + t];
        out[g * 10 + t] = acc;
    }
}

extern "C" void kernel_launch(void* const* d_in, const int* in_sizes, int n_in,
                              void* d_out, int out_size, void* d_ws, size_t ws_size,
                              hipStream_t stream) {
    const float* x        = (const float*)d_in[0];
    const int*   ei       = (const int*)d_in[1];
    const float* ew       = (const float*)d_in[2];
    const int*   batch    = (const int*)d_in[3];
    const float* metadata = (const float*)d_in[4];
    const float* W1 = (const float*)d_in[5];
    const float* b1 = (const float*)d_in[6];
    const float* W2 = (const float*)d_in[7];
    const float* b2 = (const float*)d_in[8];
    const float* Wm = (const float*)d_in[9];
    const float* bm = (const float*)d_in[10];
    const float* Wf = (const float*)d_in[11];
    const float* bf = (const float*)d_in[12];
    float* out = (float*)d_out;

    const int N = in_sizes[3];
    const int E = in_sizes[2];
    const int G = in_sizes[4] / 30;   // metadata rows (metadata.shape[0])

    auto al = [](size_t b) { return (b + 255) & ~(size_t)255; };
    size_t fixed = al((size_t)N * 8) + al((size_t)G * 96 * 4) + al((size_t)G * 4) * 2 +
                   al((size_t)N * 96 * 4) * 2 + 4096;
    int CAP = 64;
    while (CAP > 32 && fixed + al((size_t)N * CAP * 8) > ws_size) CAP -= 8;
    if (CAP > 48) CAP = 48;

    char* p = (char*)d_ws;
    size_t off = 0;
    auto carve = [&](size_t bytes) -> void* {
        void* r = p + off;
        off = (off + bytes + 255) & ~(size_t)255;
        return r;
    };
    // zero-init region: packed | sums | cnts | firstmax  (single memset)
    ull*   packed   = (ull*)carve((size_t)N * 8);
    float* sums     = (float*)carve((size_t)G * 96 * 4);
    int*   cnts     = (int*)carve((size_t)G * 4);
    int*   firstmax = (int*)carve((size_t)G * 4);
    size_t zero_end = off;
    int2*  ell  = (int2*)carve((size_t)N * CAP * 8);
    float* hbuf = (float*)carve((size_t)N * 96 * 4);
    float* h2   = (float*)carve((size_t)N * 96 * 4);

    hipMemsetAsync(packed, 0, zero_end, stream);

    int EB = (E + 255) / 256;
    int GB = (N + 127) / 128;
    int PB = (N + 255) / 256;
    int nb8 = (N + 7) / 8;

    // phase 1: GEMM1 (x@W1) || per-graph counts/first || edge scatter — all independent
    k_phase1<<<GB + PB + EB, 256, 0, stream>>>(x, W1, hbuf, ei, ew, packed, ell, CAP, E,
                                               batch, cnts, firstmax, N, GB, PB);
    // layer-1 aggregation + relu + GEMM2 fused
    k_mid<<<nb8, 256, 0, stream>>>(hbuf, ell, packed, CAP, b1, W2, h2, N);
    // layer-2 aggregation + mean-pool partial sums
    k_agg_pool<<<nb8, 256, 0, stream>>>(h2, ell, packed, CAP, b2, batch, sums, N);
    // head (separate dispatch = free device-wide release; the R7 per-block fence cost ~730 us)
    k_final<<<G, 128, 0, stream>>>(sums, cnts, firstmax, metadata, Wm, bm, Wf, bf, out, N, G);
}

// Round 9
// 266.216 us; speedup vs baseline: 3.7551x; 1.0492x over previous
//
#include <hip/hip_runtime.h>
#include <hip/hip_bf16.h>
#include <cstdint>

typedef unsigned long long ull;

// packed[d]: high 32 = count, low 32 = fixed-point (x 2^22) weighted degree sum.
#define FIXS 4194304.0f

__device__ __forceinline__ void fma4(float4& a, float s, const float4& v) {
    a.x += s * v.x; a.y += s * v.y; a.z += s * v.z; a.w += s * v.w;
}

__device__ __forceinline__ float dinv_of(ull q) {
    return rsqrtf((float)(unsigned)(q & 0xffffffffULL) * (1.0f / FIXS) + 1.0f);
}

__device__ __forceinline__ unsigned short bf16r(float f) {   // round-to-nearest-even bf16
    unsigned u = __float_as_uint(f);
    u += 0x7FFF + ((u >> 16) & 1);
    return (unsigned short)(u >> 16);
}
__device__ __forceinline__ float bf2f(unsigned short s) {
    return __uint_as_float(((unsigned)s) << 16);
}

// ---------------- device bodies ----------------

__device__ __forceinline__ void edge_body(int e, const int* __restrict__ ei, const float* __restrict__ w,
                                          ull* __restrict__ packed, int2* __restrict__ ell, int CAP, int E) {
    if (e >= E) return;
    int s = ei[e], d = ei[E + e];
    float wv = w[e];
    ull inc = (1ULL << 32) | (ull)(unsigned)(wv * FIXS + 0.5f);
    ull old = atomicAdd(&packed[d], inc);
    int pos = (int)(old >> 32);
    if (pos < CAP) ell[(size_t)d * CAP + pos] = make_int2(s, __float_as_int(wv));
}

// GEMM H[N,96] = X[N,96] @ W[96,96], 256 threads, 128 rows/block.
__device__ __forceinline__ void gemm_body(float* Ws, int bb, const float* __restrict__ X,
                                          const float* __restrict__ W, float* __restrict__ H, int N) {
    int t = threadIdx.x;
    {
        const float4* Wg = (const float4*)W;
        float4* Wl = (float4*)Ws;
        for (int i = t; i < 2304; i += 256) Wl[i] = Wg[i];
    }
    int lane = t & 63, wv = t >> 6;
    int cb = wv * 6;
    int row0 = bb * 128;
    int rA = row0 + lane, rB = row0 + 64 + lane;
    bool vA = rA < N, vB = rB < N;
    const float* xA = X + (size_t)(vA ? rA : 0) * 96;
    const float* xB = X + (size_t)(vB ? rB : 0) * 96;
    __syncthreads();
    float4 aA[6] = {}, aB[6] = {};
    const float4* W4 = (const float4*)Ws;
    for (int k0 = 0; k0 < 96; k0 += 4) {
        float4 xa = *(const float4*)(xA + k0);
        float4 xb = *(const float4*)(xB + k0);
#pragma unroll
        for (int kk = 0; kk < 4; kk++) {
            float sa = (kk == 0) ? xa.x : (kk == 1) ? xa.y : (kk == 2) ? xa.z : xa.w;
            float sb = (kk == 0) ? xb.x : (kk == 1) ? xb.y : (kk == 2) ? xb.z : xb.w;
#pragma unroll
            for (int c = 0; c < 6; c++) {
                float4 wv4 = W4[(k0 + kk) * 24 + cb + c];
                fma4(aA[c], sa, wv4);
                fma4(aB[c], sb, wv4);
            }
        }
    }
    if (vA) {
        float4* o = (float4*)(H + (size_t)rA * 96 + wv * 24);
#pragma unroll
        for (int c = 0; c < 6; c++) o[c] = aA[c];
    }
    if (vB) {
        float4* o = (float4*)(H + (size_t)rB * 96 + wv * 24);
#pragma unroll
        for (int c = 0; c < 6; c++) o[c] = aB[c];
    }
}

// leaders write counts and (N-n) max so first[g] = N - firstmax[g]; zero-init friendly.
__device__ __forceinline__ void pool_meta_body(int bb, const int* __restrict__ batch,
                                               int* __restrict__ cnts, int* __restrict__ firstmax, int N) {
    int n = bb * 256 + threadIdx.x;
    int lane = threadIdx.x & 63;
    bool valid = n < N;
    int g = valid ? batch[n] : -1;
    int gp = __shfl_up(g, 1);
    bool leader = valid && (lane == 0 || gp != g);
    ull lm = __ballot(leader);
    if (leader) {
        ull higher = (lane == 63) ? 0ULL : (lm >> (lane + 1));
        int run;
        if (higher) {
            run = __ffsll((long long)higher);
        } else {
            int waveBase = n - lane;
            int validLanes = min(64, N - waveBase);
            run = validLanes - lane;
        }
        atomicAdd(&cnts[g], run);
        atomicMax(&firstmax[g], N - n);
    }
}

// ---------------- phase 1: GEMM1 || pool_meta || edge scatter ----------------
__global__ __launch_bounds__(256) void k_phase1(const float* __restrict__ X, const float* __restrict__ W1,
                                                float* __restrict__ H,
                                                const int* __restrict__ ei, const float* __restrict__ w,
                                                ull* __restrict__ packed, int2* __restrict__ ell, int CAP, int E,
                                                const int* __restrict__ batch, int* __restrict__ cnts,
                                                int* __restrict__ firstmax, int N, int GB, int PB) {
    __shared__ __align__(16) float Ws[96 * 96];
    int b = blockIdx.x;
    if (b < GB) {
        gemm_body(Ws, b, X, W1, H, N);
    } else if (b < GB + PB) {
        pool_meta_body(b - GB, batch, cnts, firstmax, N);
    } else {
        edge_body((b - GB - PB) * 256 + threadIdx.x, ei, w, packed, ell, CAP, E);
    }
}

// ---------------- k_mid: layer-1 aggregation + bias + relu + GEMM2, fused ----------------
// 8 nodes x 32 lanes. W2 staged in LDS as bf16 (18.4 KB -> 8 blocks/CU so the
// latency-bound gather has 2x the waves of the 38.4 KB fp32 version).
__global__ __launch_bounds__(256) void k_mid(const float* __restrict__ h, const int2* __restrict__ ell,
                                             const ull* __restrict__ packed, int CAP,
                                             const float* __restrict__ bias, const float* __restrict__ W2,
                                             float* __restrict__ h2, int N) {
    __shared__ __align__(16) unsigned short Wl[96 * 96];   // bf16
    int t = threadIdx.x;
    for (int i = t; i < 2304; i += 256) {
        float4 wv4 = ((const float4*)W2)[i];
        ushort4 us;
        us.x = bf16r(wv4.x); us.y = bf16r(wv4.y); us.z = bf16r(wv4.z); us.w = bf16r(wv4.w);
        ((ushort4*)Wl)[i] = us;
    }
    __syncthreads();
    int slot = t >> 5, j = t & 31;
    int jj = (j < 24) ? j : 23;
    int n = blockIdx.x * 8 + slot;
    float4 acc = {0, 0, 0, 0};
    if (n < N) {
        ull pn = packed[n];
        int c = (int)(pn >> 32);
        float dn = dinv_of(pn), d2 = dn * dn;
        const float4* h4 = (const float4*)h;
        acc = h4[(size_t)n * 24 + jj];
        acc.x *= d2; acc.y *= d2; acc.z *= d2; acc.w *= d2;
        size_t base = (size_t)n * CAP;
        int i = 0;
        for (; i + 4 <= c; i += 4) {
            int4 p0 = *(const int4*)(ell + base + i);
            int4 p1 = *(const int4*)(ell + base + i + 2);
            ull q0 = packed[p0.x], q1 = packed[p0.z], q2 = packed[p1.x], q3 = packed[p1.z];
            float4 v0 = h4[(size_t)p0.x * 24 + jj];
            float4 v1 = h4[(size_t)p0.z * 24 + jj];
            float4 v2 = h4[(size_t)p1.x * 24 + jj];
            float4 v3 = h4[(size_t)p1.z * 24 + jj];
            fma4(acc, dinv_of(q0) * __int_as_float(p0.y) * dn, v0);
            fma4(acc, dinv_of(q1) * __int_as_float(p0.w) * dn, v1);
            fma4(acc, dinv_of(q2) * __int_as_float(p1.y) * dn, v2);
            fma4(acc, dinv_of(q3) * __int_as_float(p1.w) * dn, v3);
        }
        for (; i < c; i++) {
            int2 ev = ell[base + i];
            ull q = packed[ev.x];
            fma4(acc, dinv_of(q) * __int_as_float(ev.y) * dn, h4[(size_t)ev.x * 24 + jj]);
        }
        float4 b4 = ((const float4*)bias)[jj];
        acc.x = fmaxf(acc.x + b4.x, 0.f); acc.y = fmaxf(acc.y + b4.y, 0.f);
        acc.z = fmaxf(acc.z + b4.z, 0.f); acc.w = fmaxf(acc.w + b4.w, 0.f);
    }
    // GEMM2: out = acc_row @ W2 (row broadcast via shfl within the 32-lane group)
    float4 out = {0, 0, 0, 0};
#pragma unroll 4
    for (int k0 = 0; k0 < 96; k0 += 4) {
        int src = k0 >> 2;
        float4 s4 = make_float4(__shfl(acc.x, src, 32), __shfl(acc.y, src, 32),
                                __shfl(acc.z, src, 32), __shfl(acc.w, src, 32));
#pragma unroll
        for (int kk = 0; kk < 4; kk++) {
            float s = (kk == 0) ? s4.x : (kk == 1) ? s4.y : (kk == 2) ? s4.z : s4.w;
            ushort4 us = ((const ushort4*)Wl)[(k0 + kk) * 24 + jj];
            float4 wv4 = make_float4(bf2f(us.x), bf2f(us.y), bf2f(us.z), bf2f(us.w));
            fma4(out, s, wv4);
        }
    }
    if (n < N && j < 24) ((float4*)h2)[(size_t)n * 24 + j] = out;
}

// ---------------- Layer-2 aggregation + mean-pool partial sums ----------------
__global__ __launch_bounds__(256) void k_agg_pool(const float* __restrict__ h, const int2* __restrict__ ell,
                                                  const ull* __restrict__ packed, int CAP,
                                                  const float* __restrict__ bias,
                                                  const int* __restrict__ batch, float* __restrict__ sums, int N) {
    __shared__ float vals[8][96];
    __shared__ int gs[8];
    int slot = threadIdx.x >> 5, j = threadIdx.x & 31;
    int jj = (j < 24) ? j : 23;
    int n = blockIdx.x * 8 + slot;
    float4 acc = {0, 0, 0, 0};
    int g = -1;
    if (n < N) {
        g = batch[n];
        ull pn = packed[n];
        int c = (int)(pn >> 32);
        float dn = dinv_of(pn), d2 = dn * dn;
        const float4* h4 = (const float4*)h;
        acc = h4[(size_t)n * 24 + jj];
        acc.x *= d2; acc.y *= d2; acc.z *= d2; acc.w *= d2;
        size_t base = (size_t)n * CAP;
        int i = 0;
        for (; i + 4 <= c; i += 4) {
            int4 p0 = *(const int4*)(ell + base + i);
            int4 p1 = *(const int4*)(ell + base + i + 2);
            ull q0 = packed[p0.x], q1 = packed[p0.z], q2 = packed[p1.x], q3 = packed[p1.z];
            float4 v0 = h4[(size_t)p0.x * 24 + jj];
            float4 v1 = h4[(size_t)p0.z * 24 + jj];
            float4 v2 = h4[(size_t)p1.x * 24 + jj];
            float4 v3 = h4[(size_t)p1.z * 24 + jj];
            fma4(acc, dinv_of(q0) * __int_as_float(p0.y) * dn, v0);
            fma4(acc, dinv_of(q1) * __int_as_float(p0.w) * dn, v1);
            fma4(acc, dinv_of(q2) * __int_as_float(p1.y) * dn, v2);
            fma4(acc, dinv_of(q3) * __int_as_float(p1.w) * dn, v3);
        }
        for (; i < c; i++) {
            int2 ev = ell[base + i];
            ull q = packed[ev.x];
            fma4(acc, dinv_of(q) * __int_as_float(ev.y) * dn, h4[(size_t)ev.x * 24 + jj]);
        }
        float4 b4 = ((const float4*)bias)[jj];
        acc.x = fmaxf(acc.x + b4.x, 0.f); acc.y = fmaxf(acc.y + b4.y, 0.f);
        acc.z = fmaxf(acc.z + b4.z, 0.f); acc.w = fmaxf(acc.w + b4.w, 0.f);
    }
    if (j == 0) gs[slot] = g;
    if (j < 24) *(float4*)&vals[slot][4 * j] = acc;
    __syncthreads();
    if (threadIdx.x < 96) {
        int f = threadIdx.x;
        int g0 = gs[0];
        bool uni = true;
#pragma unroll
        for (int s = 1; s < 8; s++) uni &= (gs[s] == g0);
        if (uni) {
            if (g0 >= 0) {
                float sum = 0;
#pragma unroll
                for (int s = 0; s < 8; s++) sum += vals[s][f];
                atomicAdd(&sums[g0 * 96 + f], sum);
            }
        } else {
#pragma unroll
            for (int s = 0; s < 8; s++) {
                int gg = gs[s];
                if (gg >= 0) atomicAdd(&sums[gg * 96 + f], vals[s][f]);
            }
        }
    }
}

// ---------------- final: pooled mean + metadata MLP + head ----------------
__global__ __launch_bounds__(128) void k_final(const float* __restrict__ sums, const int* __restrict__ cnts,
                                               const int* __restrict__ firstmax, const float* __restrict__ metadata,
                                               const float* __restrict__ Wm, const float* __restrict__ bm,
                                               const float* __restrict__ Wf, const float* __restrict__ bf,
                                               float* __restrict__ out, int N, int mrows) {
    __shared__ float z[192];
    int g = blockIdx.x, t = threadIdx.x;
    if (t < 96) {
        float c = fmaxf((float)cnts[g], 1.0f);
        z[t] = sums[g * 96 + t] / c;
        unsigned fi = (unsigned)(N - firstmax[g]);
        unsigned mi = fi % (unsigned)mrows;   // mrows = metadata.shape[0] = G
        float acc = bm[t];
        for (int k = 0; k < 30; k++) acc += metadata[mi * 30 + k] * Wm[k * 96 + t];
        z[96 + t] = fmaxf(acc, 0.f);
    }
    __syncthreads();
    if (t < 10) {
        float acc = bf[t];
        for (int q = 0; q < 192; q++) acc += z[q] * Wf[q * 10 + t];
        out[g * 10 + t] = acc;
    }
}

extern "C" void kernel_launch(void* const* d_in, const int* in_sizes, int n_in,
                              void* d_out, int out_size, void* d_ws, size_t ws_size,
                              hipStream_t stream) {
    const float* x        = (const float*)d_in[0];
    const int*   ei       = (const int*)d_in[1];
    const float* ew       = (const float*)d_in[2];
    const int*   batch    = (const int*)d_in[3];
    const float* metadata = (const float*)d_in[4];
    const float* W1 = (const float*)d_in[5];
    const float* b1 = (const float*)d_in[6];
    const float* W2 = (const float*)d_in[7];
    const float* b2 = (const float*)d_in[8];
    const float* Wm = (const float*)d_in[9];
    const float* bm = (const float*)d_in[10];
    const float* Wf = (const float*)d_in[11];
    const float* bf = (const float*)d_in[12];
    float* out = (float*)d_out;

    const int N = in_sizes[3];
    const int E = in_sizes[2];
    const int G = in_sizes[4] / 30;   // metadata rows (metadata.shape[0])

    auto al = [](size_t b) { return (b + 255) & ~(size_t)255; };
    size_t fixed = al((size_t)N * 8) + al((size_t)G * 96 * 4) + al((size_t)G * 4) * 2 +
                   al((size_t)N * 96 * 4) * 2 + 4096;
    int CAP = 64;
    while (CAP > 32 && fixed + al((size_t)N * CAP * 8) > ws_size) CAP -= 8;
    if (CAP > 48) CAP = 48;

    char* p = (char*)d_ws;
    size_t off = 0;
    auto carve = [&](size_t bytes) -> void* {
        void* r = p + off;
        off = (off + bytes + 255) & ~(size_t)255;
        return r;
    };
    // zero-init region: packed | sums | cnts | firstmax  (single memset)
    ull*   packed   = (ull*)carve((size_t)N * 8);
    float* sums     = (float*)carve((size_t)G * 96 * 4);
    int*   cnts     = (int*)carve((size_t)G * 4);
    int*   firstmax = (int*)carve((size_t)G * 4);
    size_t zero_end = off;
    int2*  ell  = (int2*)carve((size_t)N * CAP * 8);
    float* hbuf = (float*)carve((size_t)N * 96 * 4);
    float* h2   = (float*)carve((size_t)N * 96 * 4);

    hipMemsetAsync(packed, 0, zero_end, stream);

    int EB = (E + 255) / 256;
    int GB = (N + 127) / 128;
    int PB = (N + 255) / 256;
    int nb8 = (N + 7) / 8;

    // phase 1: GEMM1 (x@W1) || per-graph counts/first || edge scatter — all independent
    k_phase1<<<GB + PB + EB, 256, 0, stream>>>(x, W1, hbuf, ei, ew, packed, ell, CAP, E,
                                               batch, cnts, firstmax, N, GB, PB);
    // layer-1 aggregation + relu + GEMM2 fused (W2 as bf16 in LDS: occupancy 2x)
    k_mid<<<nb8, 256, 0, stream>>>(hbuf, ell, packed, CAP, b1, W2, h2, N);
    // layer-2 aggregation + mean-pool partial sums
    k_agg_pool<<<nb8, 256, 0, stream>>>(h2, ell, packed, CAP, b2, batch, sums, N);
    // head (separate dispatch = free device-wide release; R7's per-block fence cost ~730 us)
    k_final<<<G, 128, 0, stream>>>(sums, cnts, firstmax, metadata, Wm, bm, Wf, bf, out, N, G);
}

// Round 10
// 233.718 us; speedup vs baseline: 4.2772x; 1.1390x over previous
//
#include <hip/hip_runtime.h>
#include <hip/hip_bf16.h>
#include <cstdint>

typedef unsigned long long ull;
typedef unsigned int uint;

// packed[d]: high 32 = count, low 32 = fixed-point (x 2^22) weighted degree sum.
#define FIXS 4194304.0f
#define CAPMAX 48

__device__ __forceinline__ void fma4(float4& a, float s, const float4& v) {
    a.x += s * v.x; a.y += s * v.y; a.z += s * v.z; a.w += s * v.w;
}
__device__ __forceinline__ float dinv_of(ull q) {
    return rsqrtf((float)(unsigned)(q & 0xffffffffULL) * (1.0f / FIXS) + 1.0f);
}
__device__ __forceinline__ uint bf16r(float f) {   // RNE bf16 (unbiased: pooling averages error down)
    uint u = __float_as_uint(f);
    u += 0x7FFF + ((u >> 16) & 1);
    return u >> 16;
}
__device__ __forceinline__ uint pkbf(float a, float b) { return bf16r(a) | (bf16r(b) << 16); }
__device__ __forceinline__ float blo(uint u) { return __uint_as_float(u << 16); }
__device__ __forceinline__ float bhi(uint u) { return __uint_as_float(u & 0xffff0000u); }

// ---------------- device bodies ----------------

__device__ __forceinline__ void edge_body(int e, const int* __restrict__ ei, const float* __restrict__ w,
                                          ull* __restrict__ packed, int2* __restrict__ ell, int CAP, int E) {
    if (e >= E) return;
    int s = ei[e], d = ei[E + e];
    float wv = w[e];
    ull inc = (1ULL << 32) | (ull)(unsigned)(wv * FIXS + 0.5f);
    ull old = atomicAdd(&packed[d], inc);
    int pos = (int)(old >> 32);
    if (pos < CAP) ell[(size_t)d * CAP + pos] = make_int2(s, __float_as_int(wv));
}

// GEMM1: H1[N,96](bf16) = X[N,96](fp32) @ W[96,96], 256 threads, 128 rows/block.
__device__ __forceinline__ void gemm_body(float* Ws, int bb, const float* __restrict__ X,
                                          const float* __restrict__ W, uint* __restrict__ Hb, int N) {
    int t = threadIdx.x;
    {
        const float4* Wg = (const float4*)W;
        float4* Wl = (float4*)Ws;
        for (int i = t; i < 2304; i += 256) Wl[i] = Wg[i];
    }
    int lane = t & 63, wv = t >> 6;
    int cb = wv * 6;
    int row0 = bb * 128;
    int rA = row0 + lane, rB = row0 + 64 + lane;
    bool vA = rA < N, vB = rB < N;
    const float* xA = X + (size_t)(vA ? rA : 0) * 96;
    const float* xB = X + (size_t)(vB ? rB : 0) * 96;
    __syncthreads();
    float4 aA[6] = {}, aB[6] = {};
    const float4* W4 = (const float4*)Ws;
    for (int k0 = 0; k0 < 96; k0 += 4) {
        float4 xa = *(const float4*)(xA + k0);
        float4 xb = *(const float4*)(xB + k0);
#pragma unroll
        for (int kk = 0; kk < 4; kk++) {
            float sa = (kk == 0) ? xa.x : (kk == 1) ? xa.y : (kk == 2) ? xa.z : xa.w;
            float sb = (kk == 0) ? xb.x : (kk == 1) ? xb.y : (kk == 2) ? xb.z : xb.w;
#pragma unroll
            for (int c = 0; c < 6; c++) {
                float4 wv4 = W4[(k0 + kk) * 24 + cb + c];
                fma4(aA[c], sa, wv4);
                fma4(aB[c], sb, wv4);
            }
        }
    }
    if (vA) {
        uint4* o = (uint4*)(Hb + (size_t)rA * 48 + wv * 12);
#pragma unroll
        for (int c = 0; c < 3; c++)
            o[c] = make_uint4(pkbf(aA[2*c].x, aA[2*c].y), pkbf(aA[2*c].z, aA[2*c].w),
                              pkbf(aA[2*c+1].x, aA[2*c+1].y), pkbf(aA[2*c+1].z, aA[2*c+1].w));
    }
    if (vB) {
        uint4* o = (uint4*)(Hb + (size_t)rB * 48 + wv * 12);
#pragma unroll
        for (int c = 0; c < 3; c++)
            o[c] = make_uint4(pkbf(aB[2*c].x, aB[2*c].y), pkbf(aB[2*c].z, aB[2*c].w),
                              pkbf(aB[2*c+1].x, aB[2*c+1].y), pkbf(aB[2*c+1].z, aB[2*c+1].w));
    }
}

// leaders write counts and (N-n) max so first[g] = N - firstmax[g]; zero-init friendly.
__device__ __forceinline__ void pool_meta_body(int bb, const int* __restrict__ batch,
                                               int* __restrict__ cnts, int* __restrict__ firstmax, int N) {
    int n = bb * 256 + threadIdx.x;
    int lane = threadIdx.x & 63;
    bool valid = n < N;
    int g = valid ? batch[n] : -1;
    int gp = __shfl_up(g, 1);
    bool leader = valid && (lane == 0 || gp != g);
    ull lm = __ballot(leader);
    if (leader) {
        ull higher = (lane == 63) ? 0ULL : (lm >> (lane + 1));
        int run;
        if (higher) {
            run = __ffsll((long long)higher);
        } else {
            int waveBase = n - lane;
            int validLanes = min(64, N - waveBase);
            run = validLanes - lane;
        }
        atomicAdd(&cnts[g], run);
        atomicMax(&firstmax[g], N - n);
    }
}

// ---------------- phase 1: GEMM1 || pool_meta || edge scatter ----------------
__global__ __launch_bounds__(256) void k_phase1(const float* __restrict__ X, const float* __restrict__ W1,
                                                uint* __restrict__ H1b,
                                                const int* __restrict__ ei, const float* __restrict__ w,
                                                ull* __restrict__ packed, int2* __restrict__ ell, int CAP, int E,
                                                const int* __restrict__ batch, int* __restrict__ cnts,
                                                int* __restrict__ firstmax, int N, int GB, int PB) {
    __shared__ __align__(16) float Ws[96 * 96];
    int b = blockIdx.x;
    if (b < GB) {
        gemm_body(Ws, b, X, W1, H1b, N);
    } else if (b < GB + PB) {
        pool_meta_body(b - GB, batch, cnts, firstmax, N);
    } else {
        edge_body((b - GB - PB) * 256 + threadIdx.x, ei, w, packed, ell, CAP, E);
    }
}

// ---------------- shared gather core: LDS-staged neighbors, bf16 rows ----------------
// slot = 32-lane half-wave per node. Staging lanes == gather lanes (same wave -> no barrier).
__device__ __forceinline__ float4 agg_core(int2* nbr, int slot, int j, int jo, int n,
                                           const uint* __restrict__ hb, const int2* __restrict__ ell,
                                           const ull* __restrict__ packed, int CAP,
                                           const float* __restrict__ bias) {
    ull pn = packed[n];
    int c = min((int)(pn >> 32), CAP);
    float dn = dinv_of(pn), d2 = dn * dn;
    size_t base = (size_t)n * CAP;
    for (int i = j; i < c; i += 32) {
        int2 ev = ell[base + i];
        float nw = dinv_of(packed[ev.x]) * __int_as_float(ev.y) * dn;
        nbr[i] = make_int2(ev.x * 48, __float_as_int(nw));
    }
    // self term
    uint2 su = *(const uint2*)(hb + (size_t)n * 48 + jo);
    float4 acc = make_float4(blo(su.x) * d2, bhi(su.x) * d2, blo(su.y) * d2, bhi(su.y) * d2);
    int i = 0;
    for (; i + 4 <= c; i += 4) {
        int4 e01 = *(const int4*)(nbr + i);       // broadcast LDS reads
        int4 e23 = *(const int4*)(nbr + i + 2);
        uint2 u0 = *(const uint2*)(hb + e01.x + jo);
        uint2 u1 = *(const uint2*)(hb + e01.z + jo);
        uint2 u2 = *(const uint2*)(hb + e23.x + jo);
        uint2 u3 = *(const uint2*)(hb + e23.z + jo);
        float w0 = __int_as_float(e01.y), w1 = __int_as_float(e01.w);
        float w2 = __int_as_float(e23.y), w3 = __int_as_float(e23.w);
        acc.x += w0 * blo(u0.x); acc.y += w0 * bhi(u0.x); acc.z += w0 * blo(u0.y); acc.w += w0 * bhi(u0.y);
        acc.x += w1 * blo(u1.x); acc.y += w1 * bhi(u1.x); acc.z += w1 * blo(u1.y); acc.w += w1 * bhi(u1.y);
        acc.x += w2 * blo(u2.x); acc.y += w2 * bhi(u2.x); acc.z += w2 * blo(u2.y); acc.w += w2 * bhi(u2.y);
        acc.x += w3 * blo(u3.x); acc.y += w3 * bhi(u3.x); acc.z += w3 * blo(u3.y); acc.w += w3 * bhi(u3.y);
    }
    for (; i < c; i++) {
        int2 e = nbr[i];
        uint2 u = *(const uint2*)(hb + e.x + jo);
        float nw = __int_as_float(e.y);
        acc.x += nw * blo(u.x); acc.y += nw * bhi(u.x); acc.z += nw * blo(u.y); acc.w += nw * bhi(u.y);
    }
    float4 b4 = ((const float4*)bias)[(jo >> 1)];
    acc.x = fmaxf(acc.x + b4.x, 0.f); acc.y = fmaxf(acc.y + b4.y, 0.f);
    acc.z = fmaxf(acc.z + b4.z, 0.f); acc.w = fmaxf(acc.w + b4.w, 0.f);
    return acc;
}

// ---------------- layer-1 aggregation + bias + relu -> g1 (bf16) ----------------
__global__ __launch_bounds__(256) void k_agg1(const uint* __restrict__ h1b, const int2* __restrict__ ell,
                                              const ull* __restrict__ packed, int CAP,
                                              const float* __restrict__ bias, uint* __restrict__ g1b, int N) {
    __shared__ __align__(16) int2 nbr[8][CAPMAX];
    int t = threadIdx.x;
    int slot = t >> 5, j = t & 31;
    int jj = (j < 24) ? j : 23;
    int jo = 2 * jj;
    int n = blockIdx.x * 8 + slot;
    if (n >= N) return;
    float4 acc = agg_core(nbr[slot], slot, j, jo, n, h1b, ell, packed, CAP, bias);
    if (j < 24) *(uint2*)(g1b + (size_t)n * 48 + jo) = make_uint2(pkbf(acc.x, acc.y), pkbf(acc.z, acc.w));
}

// ---------------- GEMM2: H2[N,96](bf16) = G1[N,96](bf16) @ W2, fp32 W in LDS ----------------
__global__ __launch_bounds__(256) void k_gemm2(const uint* __restrict__ Xb, const float* __restrict__ W,
                                               uint* __restrict__ Hb, int N) {
    __shared__ __align__(16) float Ws[96 * 96];
    int t = threadIdx.x;
    {
        const float4* Wg = (const float4*)W;
        float4* Wl = (float4*)Ws;
        for (int i = t; i < 2304; i += 256) Wl[i] = Wg[i];
    }
    int lane = t & 63, wv = t >> 6;
    int cb = wv * 6;
    int row0 = blockIdx.x * 128;
    int rA = row0 + lane, rB = row0 + 64 + lane;
    bool vA = rA < N, vB = rB < N;
    const uint* xA = Xb + (size_t)(vA ? rA : 0) * 48;
    const uint* xB = Xb + (size_t)(vB ? rB : 0) * 48;
    __syncthreads();
    float4 aA[6] = {}, aB[6] = {};
    const float4* W4 = (const float4*)Ws;
    for (int k0 = 0; k0 < 96; k0 += 4) {
        uint2 ua = *(const uint2*)(xA + (k0 >> 1));
        uint2 ub = *(const uint2*)(xB + (k0 >> 1));
        float fa[4] = {blo(ua.x), bhi(ua.x), blo(ua.y), bhi(ua.y)};
        float fb[4] = {blo(ub.x), bhi(ub.x), blo(ub.y), bhi(ub.y)};
#pragma unroll
        for (int kk = 0; kk < 4; kk++) {
#pragma unroll
            for (int c = 0; c < 6; c++) {
                float4 wv4 = W4[(k0 + kk) * 24 + cb + c];
                fma4(aA[c], fa[kk], wv4);
                fma4(aB[c], fb[kk], wv4);
            }
        }
    }
    if (vA) {
        uint4* o = (uint4*)(Hb + (size_t)rA * 48 + wv * 12);
#pragma unroll
        for (int c = 0; c < 3; c++)
            o[c] = make_uint4(pkbf(aA[2*c].x, aA[2*c].y), pkbf(aA[2*c].z, aA[2*c].w),
                              pkbf(aA[2*c+1].x, aA[2*c+1].y), pkbf(aA[2*c+1].z, aA[2*c+1].w));
    }
    if (vB) {
        uint4* o = (uint4*)(Hb + (size_t)rB * 48 + wv * 12);
#pragma unroll
        for (int c = 0; c < 3; c++)
            o[c] = make_uint4(pkbf(aB[2*c].x, aB[2*c].y), pkbf(aB[2*c].z, aB[2*c].w),
                              pkbf(aB[2*c+1].x, aB[2*c+1].y), pkbf(aB[2*c+1].z, aB[2*c+1].w));
    }
}

// ---------------- layer-2 aggregation + mean-pool partial sums ----------------
__global__ __launch_bounds__(256) void k_agg_pool(const uint* __restrict__ h2b, const int2* __restrict__ ell,
                                                  const ull* __restrict__ packed, int CAP,
                                                  const float* __restrict__ bias,
                                                  const int* __restrict__ batch, float* __restrict__ sums, int N) {
    __shared__ __align__(16) int2 nbr[8][CAPMAX];
    __shared__ float vals[8][96];
    __shared__ int gs[8];
    int t = threadIdx.x;
    int slot = t >> 5, j = t & 31;
    int jj = (j < 24) ? j : 23;
    int jo = 2 * jj;
    int n = blockIdx.x * 8 + slot;
    float4 acc = {0, 0, 0, 0};
    int g = -1;
    if (n < N) {
        g = batch[n];
        acc = agg_core(nbr[slot], slot, j, jo, n, h2b, ell, packed, CAP, bias);
    }
    if (j == 0) gs[slot] = g;
    if (j < 24) *(float4*)&vals[slot][4 * j] = acc;
    __syncthreads();
    if (t < 96) {
        int f = t;
        int g0 = gs[0];
        bool uni = true;
#pragma unroll
        for (int s = 1; s < 8; s++) uni &= (gs[s] == g0);
        if (uni) {
            if (g0 >= 0) {
                float sum = 0;
#pragma unroll
                for (int s = 0; s < 8; s++) sum += vals[s][f];
                atomicAdd(&sums[g0 * 96 + f], sum);
            }
        } else {
#pragma unroll
            for (int s = 0; s < 8; s++) {
                int gg = gs[s];
                if (gg >= 0) atomicAdd(&sums[gg * 96 + f], vals[s][f]);
            }
        }
    }
}

// ---------------- final: pooled mean + metadata MLP + head ----------------
__global__ __launch_bounds__(128) void k_final(const float* __restrict__ sums, const int* __restrict__ cnts,
                                               const int* __restrict__ firstmax, const float* __restrict__ metadata,
                                               const float* __restrict__ Wm, const float* __restrict__ bm,
                                               const float* __restrict__ Wf, const float* __restrict__ bf,
                                               float* __restrict__ out, int N, int mrows) {
    __shared__ float z[192];
    int g = blockIdx.x, t = threadIdx.x;
    if (t < 96) {
        float c = fmaxf((float)cnts[g], 1.0f);
        z[t] = sums[g * 96 + t] / c;
        unsigned fi = (unsigned)(N - firstmax[g]);
        unsigned mi = fi % (unsigned)mrows;   // mrows = metadata.shape[0] = G
        float acc = bm[t];
        for (int k = 0; k < 30; k++) acc += metadata[mi * 30 + k] * Wm[k * 96 + t];
        z[96 + t] = fmaxf(acc, 0.f);
    }
    __syncthreads();
    if (t < 10) {
        float acc = bf[t];
        for (int q = 0; q < 192; q++) acc += z[q] * Wf[q * 10 + t];
        out[g * 10 + t] = acc;
    }
}

extern "C" void kernel_launch(void* const* d_in, const int* in_sizes, int n_in,
                              void* d_out, int out_size, void* d_ws, size_t ws_size,
                              hipStream_t stream) {
    const float* x        = (const float*)d_in[0];
    const int*   ei       = (const int*)d_in[1];
    const float* ew       = (const float*)d_in[2];
    const int*   batch    = (const int*)d_in[3];
    const float* metadata = (const float*)d_in[4];
    const float* W1 = (const float*)d_in[5];
    const float* b1 = (const float*)d_in[6];
    const float* W2 = (const float*)d_in[7];
    const float* b2 = (const float*)d_in[8];
    const float* Wm = (const float*)d_in[9];
    const float* bm = (const float*)d_in[10];
    const float* Wf = (const float*)d_in[11];
    const float* bf = (const float*)d_in[12];
    float* out = (float*)d_out;

    const int N = in_sizes[3];
    const int E = in_sizes[2];
    const int G = in_sizes[4] / 30;   // metadata rows (metadata.shape[0])

    auto al = [](size_t b) { return (b + 255) & ~(size_t)255; };
    size_t fixed = al((size_t)N * 8) + al((size_t)G * 96 * 4) + al((size_t)G * 4) * 2 +
                   al((size_t)N * 48 * 4) * 3 + 4096;
    int CAP = CAPMAX;
    while (CAP > 32 && fixed + al((size_t)N * CAP * 8) > ws_size) CAP -= 8;
    if (CAP > CAPMAX) CAP = CAPMAX;

    char* p = (char*)d_ws;
    size_t off = 0;
    auto carve = [&](size_t bytes) -> void* {
        void* r = p + off;
        off = (off + bytes + 255) & ~(size_t)255;
        return r;
    };
    // zero-init region: packed | sums | cnts | firstmax  (single memset)
    ull*   packed   = (ull*)carve((size_t)N * 8);
    float* sums     = (float*)carve((size_t)G * 96 * 4);
    int*   cnts     = (int*)carve((size_t)G * 4);
    int*   firstmax = (int*)carve((size_t)G * 4);
    size_t zero_end = off;
    int2*  ell  = (int2*)carve((size_t)N * CAP * 8);
    uint*  h1b  = (uint*)carve((size_t)N * 48 * 4);   // bf16 rows, 48 uints/row
    uint*  g1b  = (uint*)carve((size_t)N * 48 * 4);
    uint*  h2b  = (uint*)carve((size_t)N * 48 * 4);

    hipMemsetAsync(packed, 0, zero_end, stream);

    int EB = (E + 255) / 256;
    int GB = (N + 127) / 128;
    int PB = (N + 255) / 256;
    int nb8 = (N + 7) / 8;

    // phase 1: GEMM1 (x@W1 -> bf16) || per-graph counts/first || edge scatter
    k_phase1<<<GB + PB + EB, 256, 0, stream>>>(x, W1, h1b, ei, ew, packed, ell, CAP, E,
                                               batch, cnts, firstmax, N, GB, PB);
    // layer-1 aggregation (LDS-staged neighbor norms, bf16 gather)
    k_agg1<<<nb8, 256, 0, stream>>>(h1b, ell, packed, CAP, b1, g1b, N);
    // GEMM2 (register-tiled, bf16 in/out)
    k_gemm2<<<GB, 256, 0, stream>>>(g1b, W2, h2b, N);
    // layer-2 aggregation + mean-pool
    k_agg_pool<<<nb8, 256, 0, stream>>>(h2b, ell, packed, CAP, b2, batch, sums, N);
    // head
    k_final<<<G, 128, 0, stream>>>(sums, cnts, firstmax, metadata, Wm, bm, Wf, bf, out, N, G);
}

// Round 11
// 230.321 us; speedup vs baseline: 4.3403x; 1.0147x over previous
//
#include <hip/hip_runtime.h>
#include <hip/hip_bf16.h>
#include <cstdint>

typedef unsigned long long ull;
typedef unsigned int uint;

// packed[d]: high 32 = count, low 32 = fixed-point (x 2^22) weighted degree sum.
#define FIXS 4194304.0f
#define CAPMAX 48

__device__ __forceinline__ void fma4(float4& a, float s, const float4& v) {
    a.x += s * v.x; a.y += s * v.y; a.z += s * v.z; a.w += s * v.w;
}
__device__ __forceinline__ float dinv_of(ull q) {
    return rsqrtf((float)(unsigned)(q & 0xffffffffULL) * (1.0f / FIXS) + 1.0f);
}
__device__ __forceinline__ uint bf16r(float f) {   // RNE bf16
    uint u = __float_as_uint(f);
    u += 0x7FFF + ((u >> 16) & 1);
    return u >> 16;
}
__device__ __forceinline__ uint pkbf(float a, float b) { return bf16r(a) | (bf16r(b) << 16); }
__device__ __forceinline__ float blo(uint u) { return __uint_as_float(u << 16); }
__device__ __forceinline__ float bhi(uint u) { return __uint_as_float(u & 0xffff0000u); }

// ---------------- device bodies ----------------

__device__ __forceinline__ void edge_body(int e, const int* __restrict__ ei, const float* __restrict__ w,
                                          ull* __restrict__ packed, int2* __restrict__ ell, int CAP, int E) {
    if (e >= E) return;
    int s = ei[e], d = ei[E + e];
    float wv = w[e];
    ull inc = (1ULL << 32) | (ull)(unsigned)(wv * FIXS + 0.5f);
    ull old = atomicAdd(&packed[d], inc);
    int pos = (int)(old >> 32);
    if (pos < CAP) ell[(size_t)d * CAP + pos] = make_int2(s, __float_as_int(wv));
}

// GEMM1: H1[N,96](bf16) = X[N,96](fp32) @ W[96,96], 256 threads, 128 rows/block.
__device__ __forceinline__ void gemm_body(float* Ws, int bb, const float* __restrict__ X,
                                          const float* __restrict__ W, uint* __restrict__ Hb, int N) {
    int t = threadIdx.x;
    {
        const float4* Wg = (const float4*)W;
        float4* Wl = (float4*)Ws;
        for (int i = t; i < 2304; i += 256) Wl[i] = Wg[i];
    }
    int lane = t & 63, wv = t >> 6;
    int cb = wv * 6;
    int row0 = bb * 128;
    int rA = row0 + lane, rB = row0 + 64 + lane;
    bool vA = rA < N, vB = rB < N;
    const float* xA = X + (size_t)(vA ? rA : 0) * 96;
    const float* xB = X + (size_t)(vB ? rB : 0) * 96;
    __syncthreads();
    float4 aA[6] = {}, aB[6] = {};
    const float4* W4 = (const float4*)Ws;
    for (int k0 = 0; k0 < 96; k0 += 4) {
        float4 xa = *(const float4*)(xA + k0);
        float4 xb = *(const float4*)(xB + k0);
#pragma unroll
        for (int kk = 0; kk < 4; kk++) {
            float sa = (kk == 0) ? xa.x : (kk == 1) ? xa.y : (kk == 2) ? xa.z : xa.w;
            float sb = (kk == 0) ? xb.x : (kk == 1) ? xb.y : (kk == 2) ? xb.z : xb.w;
#pragma unroll
            for (int c = 0; c < 6; c++) {
                float4 wv4 = W4[(k0 + kk) * 24 + cb + c];
                fma4(aA[c], sa, wv4);
                fma4(aB[c], sb, wv4);
            }
        }
    }
    if (vA) {
        uint4* o = (uint4*)(Hb + (size_t)rA * 48 + wv * 12);
#pragma unroll
        for (int c = 0; c < 3; c++)
            o[c] = make_uint4(pkbf(aA[2*c].x, aA[2*c].y), pkbf(aA[2*c].z, aA[2*c].w),
                              pkbf(aA[2*c+1].x, aA[2*c+1].y), pkbf(aA[2*c+1].z, aA[2*c+1].w));
    }
    if (vB) {
        uint4* o = (uint4*)(Hb + (size_t)rB * 48 + wv * 12);
#pragma unroll
        for (int c = 0; c < 3; c++)
            o[c] = make_uint4(pkbf(aB[2*c].x, aB[2*c].y), pkbf(aB[2*c].z, aB[2*c].w),
                              pkbf(aB[2*c+1].x, aB[2*c+1].y), pkbf(aB[2*c+1].z, aB[2*c+1].w));
    }
}

// leaders write counts and (N-n) max so first[g] = N - firstmax[g]; zero-init friendly.
__device__ __forceinline__ void pool_meta_body(int bb, const int* __restrict__ batch,
                                               int* __restrict__ cnts, int* __restrict__ firstmax, int N) {
    int n = bb * 256 + threadIdx.x;
    int lane = threadIdx.x & 63;
    bool valid = n < N;
    int g = valid ? batch[n] : -1;
    int gp = __shfl_up(g, 1);
    bool leader = valid && (lane == 0 || gp != g);
    ull lm = __ballot(leader);
    if (leader) {
        ull higher = (lane == 63) ? 0ULL : (lm >> (lane + 1));
        int run;
        if (higher) {
            run = __ffsll((long long)higher);
        } else {
            int waveBase = n - lane;
            int validLanes = min(64, N - waveBase);
            run = validLanes - lane;
        }
        atomicAdd(&cnts[g], run);
        atomicMax(&firstmax[g], N - n);
    }
}

// ---------------- phase 1: GEMM1 || pool_meta || edge scatter ----------------
__global__ __launch_bounds__(256) void k_phase1(const float* __restrict__ X, const float* __restrict__ W1,
                                                uint* __restrict__ H1b,
                                                const int* __restrict__ ei, const float* __restrict__ w,
                                                ull* __restrict__ packed, int2* __restrict__ ell, int CAP, int E,
                                                const int* __restrict__ batch, int* __restrict__ cnts,
                                                int* __restrict__ firstmax, int N, int GB, int PB) {
    __shared__ __align__(16) float Ws[96 * 96];
    int b = blockIdx.x;
    if (b < GB) {
        gemm_body(Ws, b, X, W1, H1b, N);
    } else if (b < GB + PB) {
        pool_meta_body(b - GB, batch, cnts, firstmax, N);
    } else {
        edge_body((b - GB - PB) * 256 + threadIdx.x, ei, w, packed, ell, CAP, E);
    }
}

// ---------------- gather core (post-barrier part): 24 lanes per node ----------------
// lane j owns features [2j, 2j+2) as one uint2 (4 bf16). nbr already staged in LDS.
__device__ __forceinline__ float4 gather24(const int2* nbr, int j, int c, int n, float dn, float d2,
                                           const uint* __restrict__ hb, const float* __restrict__ bias) {
    int jo = 2 * j;
    uint2 su = *(const uint2*)(hb + (size_t)n * 48 + jo);
    float4 acc = make_float4(blo(su.x) * d2, bhi(su.x) * d2, blo(su.y) * d2, bhi(su.y) * d2);
    int i = 0;
    for (; i + 8 <= c; i += 8) {
        int4 e01 = *(const int4*)(nbr + i);
        int4 e23 = *(const int4*)(nbr + i + 2);
        int4 e45 = *(const int4*)(nbr + i + 4);
        int4 e67 = *(const int4*)(nbr + i + 6);
        uint2 u0 = *(const uint2*)(hb + e01.x + jo);
        uint2 u1 = *(const uint2*)(hb + e01.z + jo);
        uint2 u2 = *(const uint2*)(hb + e23.x + jo);
        uint2 u3 = *(const uint2*)(hb + e23.z + jo);
        uint2 u4 = *(const uint2*)(hb + e45.x + jo);
        uint2 u5 = *(const uint2*)(hb + e45.z + jo);
        uint2 u6 = *(const uint2*)(hb + e67.x + jo);
        uint2 u7 = *(const uint2*)(hb + e67.z + jo);
        float w0 = __int_as_float(e01.y), w1 = __int_as_float(e01.w);
        float w2 = __int_as_float(e23.y), w3 = __int_as_float(e23.w);
        float w4 = __int_as_float(e45.y), w5 = __int_as_float(e45.w);
        float w6 = __int_as_float(e67.y), w7 = __int_as_float(e67.w);
        acc.x += w0 * blo(u0.x); acc.y += w0 * bhi(u0.x); acc.z += w0 * blo(u0.y); acc.w += w0 * bhi(u0.y);
        acc.x += w1 * blo(u1.x); acc.y += w1 * bhi(u1.x); acc.z += w1 * blo(u1.y); acc.w += w1 * bhi(u1.y);
        acc.x += w2 * blo(u2.x); acc.y += w2 * bhi(u2.x); acc.z += w2 * blo(u2.y); acc.w += w2 * bhi(u2.y);
        acc.x += w3 * blo(u3.x); acc.y += w3 * bhi(u3.x); acc.z += w3 * blo(u3.y); acc.w += w3 * bhi(u3.y);
        acc.x += w4 * blo(u4.x); acc.y += w4 * bhi(u4.x); acc.z += w4 * blo(u4.y); acc.w += w4 * bhi(u4.y);
        acc.x += w5 * blo(u5.x); acc.y += w5 * bhi(u5.x); acc.z += w5 * blo(u5.y); acc.w += w5 * bhi(u5.y);
        acc.x += w6 * blo(u6.x); acc.y += w6 * bhi(u6.x); acc.z += w6 * blo(u6.y); acc.w += w6 * bhi(u6.y);
        acc.x += w7 * blo(u7.x); acc.y += w7 * bhi(u7.x); acc.z += w7 * blo(u7.y); acc.w += w7 * bhi(u7.y);
    }
    for (; i + 2 <= c; i += 2) {
        int4 e01 = *(const int4*)(nbr + i);
        uint2 u0 = *(const uint2*)(hb + e01.x + jo);
        uint2 u1 = *(const uint2*)(hb + e01.z + jo);
        float w0 = __int_as_float(e01.y), w1 = __int_as_float(e01.w);
        acc.x += w0 * blo(u0.x); acc.y += w0 * bhi(u0.x); acc.z += w0 * blo(u0.y); acc.w += w0 * bhi(u0.y);
        acc.x += w1 * blo(u1.x); acc.y += w1 * bhi(u1.x); acc.z += w1 * blo(u1.y); acc.w += w1 * bhi(u1.y);
    }
    if (i < c) {
        int2 e = nbr[i];
        uint2 u = *(const uint2*)(hb + e.x + jo);
        float nw = __int_as_float(e.y);
        acc.x += nw * blo(u.x); acc.y += nw * bhi(u.x); acc.z += nw * blo(u.y); acc.w += nw * bhi(u.y);
    }
    float4 b4 = ((const float4*)bias)[j];
    acc.x = fmaxf(acc.x + b4.x, 0.f); acc.y = fmaxf(acc.y + b4.y, 0.f);
    acc.z = fmaxf(acc.z + b4.z, 0.f); acc.w = fmaxf(acc.w + b4.w, 0.f);
    return acc;
}

// ---------------- layer-1 aggregation + bias + relu -> g1 (bf16) ----------------
// 192 threads = 8 nodes x 24 lanes (slots span waves -> barrier between stage & gather).
__global__ __launch_bounds__(192) void k_agg1(const uint* __restrict__ h1b, const int2* __restrict__ ell,
                                              const ull* __restrict__ packed, int CAP,
                                              const float* __restrict__ bias, uint* __restrict__ g1b, int N) {
    __shared__ __align__(16) int2 nbr[8][CAPMAX];
    int t = threadIdx.x;
    int slot = t / 24, j = t - slot * 24;
    int n = blockIdx.x * 8 + slot;
    bool valid = n < N;
    ull pn = valid ? packed[n] : 0;
    int c = valid ? min((int)(pn >> 32), CAP) : 0;
    float dn = dinv_of(pn), d2 = dn * dn;
    if (valid) {
        size_t base = (size_t)n * CAP;
        for (int i = j; i < c; i += 24) {
            int2 ev = ell[base + i];
            float nw = dinv_of(packed[ev.x]) * __int_as_float(ev.y) * dn;
            nbr[slot][i] = make_int2(ev.x * 48, __float_as_int(nw));
        }
    }
    __syncthreads();
    if (!valid) return;
    float4 acc = gather24(nbr[slot], j, c, n, dn, d2, h1b, bias);
    *(uint2*)(g1b + (size_t)n * 48 + 2 * j) = make_uint2(pkbf(acc.x, acc.y), pkbf(acc.z, acc.w));
}

// ---------------- GEMM2: H2[N,96](bf16) = G1[N,96](bf16) @ W2, fp32 W in LDS ----------------
__global__ __launch_bounds__(256) void k_gemm2(const uint* __restrict__ Xb, const float* __restrict__ W,
                                               uint* __restrict__ Hb, int N) {
    __shared__ __align__(16) float Ws[96 * 96];
    int t = threadIdx.x;
    {
        const float4* Wg = (const float4*)W;
        float4* Wl = (float4*)Ws;
        for (int i = t; i < 2304; i += 256) Wl[i] = Wg[i];
    }
    int lane = t & 63, wv = t >> 6;
    int cb = wv * 6;
    int row0 = blockIdx.x * 128;
    int rA = row0 + lane, rB = row0 + 64 + lane;
    bool vA = rA < N, vB = rB < N;
    const uint* xA = Xb + (size_t)(vA ? rA : 0) * 48;
    const uint* xB = Xb + (size_t)(vB ? rB : 0) * 48;
    __syncthreads();
    float4 aA[6] = {}, aB[6] = {};
    const float4* W4 = (const float4*)Ws;
    for (int k0 = 0; k0 < 96; k0 += 8) {
        uint4 ua = *(const uint4*)(xA + (k0 >> 1));
        uint4 ub = *(const uint4*)(xB + (k0 >> 1));
        float fa[8] = {blo(ua.x), bhi(ua.x), blo(ua.y), bhi(ua.y), blo(ua.z), bhi(ua.z), blo(ua.w), bhi(ua.w)};
        float fb[8] = {blo(ub.x), bhi(ub.x), blo(ub.y), bhi(ub.y), blo(ub.z), bhi(ub.z), blo(ub.w), bhi(ub.w)};
#pragma unroll
        for (int kk = 0; kk < 8; kk++) {
#pragma unroll
            for (int c = 0; c < 6; c++) {
                float4 wv4 = W4[(k0 + kk) * 24 + cb + c];
                fma4(aA[c], fa[kk], wv4);
                fma4(aB[c], fb[kk], wv4);
            }
        }
    }
    if (vA) {
        uint4* o = (uint4*)(Hb + (size_t)rA * 48 + wv * 12);
#pragma unroll
        for (int c = 0; c < 3; c++)
            o[c] = make_uint4(pkbf(aA[2*c].x, aA[2*c].y), pkbf(aA[2*c].z, aA[2*c].w),
                              pkbf(aA[2*c+1].x, aA[2*c+1].y), pkbf(aA[2*c+1].z, aA[2*c+1].w));
    }
    if (vB) {
        uint4* o = (uint4*)(Hb + (size_t)rB * 48 + wv * 12);
#pragma unroll
        for (int c = 0; c < 3; c++)
            o[c] = make_uint4(pkbf(aB[2*c].x, aB[2*c].y), pkbf(aB[2*c].z, aB[2*c].w),
                              pkbf(aB[2*c+1].x, aB[2*c+1].y), pkbf(aB[2*c+1].z, aB[2*c+1].w));
    }
}

// ---------------- layer-2 aggregation + mean-pool partial sums ----------------
__global__ __launch_bounds__(192) void k_agg_pool(const uint* __restrict__ h2b, const int2* __restrict__ ell,
                                                  const ull* __restrict__ packed, int CAP,
                                                  const float* __restrict__ bias,
                                                  const int* __restrict__ batch, float* __restrict__ sums, int N) {
    __shared__ __align__(16) int2 nbr[8][CAPMAX];
    __shared__ float vals[8][96];
    __shared__ int gs[8];
    int t = threadIdx.x;
    int slot = t / 24, j = t - slot * 24;
    int n = blockIdx.x * 8 + slot;
    bool valid = n < N;
    int g = valid ? batch[n] : -1;
    ull pn = valid ? packed[n] : 0;
    int c = valid ? min((int)(pn >> 32), CAP) : 0;
    float dn = dinv_of(pn), d2 = dn * dn;
    if (valid) {
        size_t base = (size_t)n * CAP;
        for (int i = j; i < c; i += 24) {
            int2 ev = ell[base + i];
            float nw = dinv_of(packed[ev.x]) * __int_as_float(ev.y) * dn;
            nbr[slot][i] = make_int2(ev.x * 48, __float_as_int(nw));
        }
    }
    __syncthreads();
    float4 acc = {0, 0, 0, 0};
    if (valid) acc = gather24(nbr[slot], j, c, n, dn, d2, h2b, bias);
    if (j == 0) gs[slot] = g;
    *(float4*)&vals[slot][4 * j] = acc;
    __syncthreads();
    if (t < 96) {
        int f = t;
        int g0 = gs[0];
        bool uni = true;
#pragma unroll
        for (int s = 1; s < 8; s++) uni &= (gs[s] == g0);
        if (uni) {
            if (g0 >= 0) {
                float sum = 0;
#pragma unroll
                for (int s = 0; s < 8; s++) sum += vals[s][f];
                atomicAdd(&sums[g0 * 96 + f], sum);
            }
        } else {
#pragma unroll
            for (int s = 0; s < 8; s++) {
                int gg = gs[s];
                if (gg >= 0) atomicAdd(&sums[gg * 96 + f], vals[s][f]);
            }
        }
    }
}

// ---------------- final: pooled mean + metadata MLP + head ----------------
__global__ __launch_bounds__(128) void k_final(const float* __restrict__ sums, const int* __restrict__ cnts,
                                               const int* __restrict__ firstmax, const float* __restrict__ metadata,
                                               const float* __restrict__ Wm, const float* __restrict__ bm,
                                               const float* __restrict__ Wf, const float* __restrict__ bf,
                                               float* __restrict__ out, int N, int mrows) {
    __shared__ float z[192];
    int g = blockIdx.x, t = threadIdx.x;
    if (t < 96) {
        float c = fmaxf((float)cnts[g], 1.0f);
        z[t] = sums[g * 96 + t] / c;
        unsigned fi = (unsigned)(N - firstmax[g]);
        unsigned mi = fi % (unsigned)mrows;   // mrows = metadata.shape[0] = G
        float acc = bm[t];
        for (int k = 0; k < 30; k++) acc += metadata[mi * 30 + k] * Wm[k * 96 + t];
        z[96 + t] = fmaxf(acc, 0.f);
    }
    __syncthreads();
    if (t < 10) {
        float acc = bf[t];
        for (int q = 0; q < 192; q++) acc += z[q] * Wf[q * 10 + t];
        out[g * 10 + t] = acc;
    }
}

extern "C" void kernel_launch(void* const* d_in, const int* in_sizes, int n_in,
                              void* d_out, int out_size, void* d_ws, size_t ws_size,
                              hipStream_t stream) {
    const float* x        = (const float*)d_in[0];
    const int*   ei       = (const int*)d_in[1];
    const float* ew       = (const float*)d_in[2];
    const int*   batch    = (const int*)d_in[3];
    const float* metadata = (const float*)d_in[4];
    const float* W1 = (const float*)d_in[5];
    const float* b1 = (const float*)d_in[6];
    const float* W2 = (const float*)d_in[7];
    const float* b2 = (const float*)d_in[8];
    const float* Wm = (const float*)d_in[9];
    const float* bm = (const float*)d_in[10];
    const float* Wf = (const float*)d_in[11];
    const float* bf = (const float*)d_in[12];
    float* out = (float*)d_out;

    const int N = in_sizes[3];
    const int E = in_sizes[2];
    const int G = in_sizes[4] / 30;   // metadata rows (metadata.shape[0])

    auto al = [](size_t b) { return (b + 255) & ~(size_t)255; };
    size_t fixed = al((size_t)N * 8) + al((size_t)G * 96 * 4) + al((size_t)G * 4) * 2 +
                   al((size_t)N * 48 * 4) * 3 + 4096;
    int CAP = CAPMAX;
    while (CAP > 32 && fixed + al((size_t)N * CAP * 8) > ws_size) CAP -= 8;
    if (CAP > CAPMAX) CAP = CAPMAX;

    char* p = (char*)d_ws;
    size_t off = 0;
    auto carve = [&](size_t bytes) -> void* {
        void* r = p + off;
        off = (off + bytes + 255) & ~(size_t)255;
        return r;
    };
    // zero-init region: packed | sums | cnts | firstmax  (single memset)
    ull*   packed   = (ull*)carve((size_t)N * 8);
    float* sums     = (float*)carve((size_t)G * 96 * 4);
    int*   cnts     = (int*)carve((size_t)G * 4);
    int*   firstmax = (int*)carve((size_t)G * 4);
    size_t zero_end = off;
    int2*  ell  = (int2*)carve((size_t)N * CAP * 8);
    uint*  h1b  = (uint*)carve((size_t)N * 48 * 4);   // bf16 rows, 48 uints/row
    uint*  g1b  = (uint*)carve((size_t)N * 48 * 4);
    uint*  h2b  = (uint*)carve((size_t)N * 48 * 4);

    hipMemsetAsync(packed, 0, zero_end, stream);

    int EB = (E + 255) / 256;
    int GB = (N + 127) / 128;
    int PB = (N + 255) / 256;
    int nb8 = (N + 7) / 8;

    // phase 1: GEMM1 (x@W1 -> bf16) || per-graph counts/first || edge scatter
    k_phase1<<<GB + PB + EB, 256, 0, stream>>>(x, W1, h1b, ei, ew, packed, ell, CAP, E,
                                               batch, cnts, firstmax, N, GB, PB);
    // layer-1 aggregation (24-lane slots, LDS-staged norms, unroll-8 bf16 gather)
    k_agg1<<<nb8, 192, 0, stream>>>(h1b, ell, packed, CAP, b1, g1b, N);
    // GEMM2 (register-tiled, bf16 in/out, uint4 k-loads)
    k_gemm2<<<GB, 256, 0, stream>>>(g1b, W2, h2b, N);
    // layer-2 aggregation + mean-pool
    k_agg_pool<<<nb8, 192, 0, stream>>>(h2b, ell, packed, CAP, b2, batch, sums, N);
    // head
    k_final<<<G, 128, 0, stream>>>(sums, cnts, firstmax, metadata, Wm, bm, Wf, bf, out, N, G);
}